// Round 4
// baseline (128.982 us; speedup 1.0000x reference)
//
#include <hip/hip_runtime.h>

// GraphSAGE forward, 3 layers. R4: factored structure.
// Per layer (linearity of matmul):
//   K1 dense:  U = h @ Wtop,  Z = h @ (Wbot/16)   (streamed MFMA GEMM)
//   K2 gather: out[n] = act(U[n] + sum_k Z[adj[k][n]])  (pure gather-sum)

#define KNBR 16

typedef __attribute__((ext_vector_type(8))) short short8;
typedef __attribute__((ext_vector_type(4))) float f32x4;

__device__ inline float bf2f(unsigned short u) {
    union { unsigned int i; float f; } c; c.i = ((unsigned int)u) << 16; return c.f;
}
__device__ inline unsigned short f2bf(float f) {
    union { float f; unsigned int i; } c; c.f = f;
    unsigned int u = c.i;
    u += 0x7FFFu + ((u >> 16) & 1u);   // RNE
    return (unsigned short)(u >> 16);
}
__device__ inline void acc8(uint4 v, float* a) {
    a[0] += bf2f((unsigned short)(v.x & 0xFFFFu));
    a[1] += bf2f((unsigned short)(v.x >> 16));
    a[2] += bf2f((unsigned short)(v.y & 0xFFFFu));
    a[3] += bf2f((unsigned short)(v.y >> 16));
    a[4] += bf2f((unsigned short)(v.z & 0xFFFFu));
    a[5] += bf2f((unsigned short)(v.z >> 16));
    a[6] += bf2f((unsigned short)(v.w & 0xFFFFu));
    a[7] += bf2f((unsigned short)(v.w >> 16));
}

// ---------------- prep: combined transposed weights ----------------
// Wc[c][k], c in [0,2FO), k in [0,128):  c<FO -> W[k][c];  c>=FO -> W[128+k][c-FO]/16
__device__ inline void build_wc(const float* __restrict__ W, unsigned short* __restrict__ Wc,
                                int FO, int loc) {
    const int c = loc >> 7;
    const int k = loc & 127;
    float v = (c < FO) ? W[(size_t)k * FO + c]
                       : W[(size_t)(128 + k) * FO + (c - FO)] * 0.0625f;
    Wc[loc] = f2bf(v);
}

__global__ __launch_bounds__(256)
void wc_all_kernel(const float* __restrict__ W0, const float* __restrict__ W1,
                   const float* __restrict__ W2,
                   unsigned short* __restrict__ Wc0, unsigned short* __restrict__ Wc1,
                   unsigned short* __restrict__ Wc2) {
    int id = blockIdx.x * 256 + threadIdx.x;
    if (id < 32768)      build_wc(W0, Wc0, 128, id);
    else if (id < 65536) build_wc(W1, Wc1, 128, id - 32768);
    else if (id < 81920) build_wc(W2, Wc2, 64,  id - 65536);
}

// ---------------- K1: dense GEMM [64 x 128] @ [128 x 2FO] ----------------

template<bool INF32, int FO>
__global__ __launch_bounds__(256, 4)
void dense_kernel(const void* __restrict__ hin,          // [N][128] f32 or bf16
                  const unsigned short* __restrict__ Wc, // [2FO][128] bf16
                  unsigned short* __restrict__ U,        // [N][FO] bf16
                  unsigned short* __restrict__ Z,        // [N][FO] bf16
                  int N)
{
    __shared__ unsigned short A[64][136];   // 272B row stride: bank-quad spread, 2-way max
    const int tid  = threadIdx.x;
    const int base = blockIdx.x * 64;

    // stage 64x128 bf16 tile
    {
        const int l16 = tid & 15;
        const int r0  = tid >> 4;
        #pragma unroll
        for (int p = 0; p < 4; ++p) {
            const int r = r0 + p * 16;
            int n = base + r; if (n >= N) n = N - 1;
            if (INF32) {
                const float* xf = (const float*)hin;
                const float4 a = *reinterpret_cast<const float4*>(&xf[(size_t)n * 128 + l16 * 8]);
                const float4 b = *reinterpret_cast<const float4*>(&xf[(size_t)n * 128 + l16 * 8 + 4]);
                uint4 o;
                o.x = (unsigned int)f2bf(a.x) | ((unsigned int)f2bf(a.y) << 16);
                o.y = (unsigned int)f2bf(a.z) | ((unsigned int)f2bf(a.w) << 16);
                o.z = (unsigned int)f2bf(b.x) | ((unsigned int)f2bf(b.y) << 16);
                o.w = (unsigned int)f2bf(b.z) | ((unsigned int)f2bf(b.w) << 16);
                *reinterpret_cast<uint4*>(&A[r][l16 * 8]) = o;
            } else {
                const unsigned short* hb = (const unsigned short*)hin;
                *reinterpret_cast<uint4*>(&A[r][l16 * 8]) =
                    *reinterpret_cast<const uint4*>(&hb[(size_t)n * 128 + l16 * 8]);
            }
        }
    }
    __syncthreads();

    constexpr int NCT = (2 * FO) / 64;      // 16-col tiles per wave: 4 (FO=128) / 2 (FO=64)
    const int wv  = tid >> 6;
    const int l   = tid & 63;
    const int l15 = l & 15;
    const int kg  = l >> 4;

    f32x4 acc[4][NCT];
    #pragma unroll
    for (int rt = 0; rt < 4; ++rt)
        #pragma unroll
        for (int ct = 0; ct < NCT; ++ct)
            acc[rt][ct] = (f32x4){0.f, 0.f, 0.f, 0.f};

    const unsigned short* wbase[NCT];
    #pragma unroll
    for (int ct = 0; ct < NCT; ++ct) {
        const int col = (wv * NCT + ct) * 16 + l15;
        wbase[ct] = Wc + (size_t)col * 128 + kg * 8;
    }

    #pragma unroll
    for (int ks = 0; ks < 4; ++ks) {
        short8 b[NCT];
        #pragma unroll
        for (int ct = 0; ct < NCT; ++ct)
            b[ct] = *reinterpret_cast<const short8*>(wbase[ct] + ks * 32);
        #pragma unroll
        for (int rt = 0; rt < 4; ++rt) {
            const short8 a = *reinterpret_cast<const short8*>(&A[rt * 16 + l15][ks * 32 + kg * 8]);
            #pragma unroll
            for (int ct = 0; ct < NCT; ++ct)
                acc[rt][ct] = __builtin_amdgcn_mfma_f32_16x16x32_bf16(a, b[ct], acc[rt][ct], 0, 0, 0);
        }
    }

    // epilogue: col = b-side (lane&15), row = 4*(lane>>4)+reg
    #pragma unroll
    for (int rt = 0; rt < 4; ++rt) {
        #pragma unroll
        for (int ct = 0; ct < NCT; ++ct) {
            const int col = (wv * NCT + ct) * 16 + l15;
            #pragma unroll
            for (int r = 0; r < 4; ++r) {
                const int row = rt * 16 + kg * 4 + r;
                const int n   = base + row;
                if (n < N) {
                    const unsigned short v = f2bf(acc[rt][ct][r]);
                    if (col < FO) U[(size_t)n * FO + col] = v;
                    else          Z[(size_t)n * FO + (col - FO)] = v;
                }
            }
        }
    }
}

// ---------------- K2: gather-sum ----------------
// out[n] = act(U[n] + sum_k Z[adj[k][n]])   (1/16 already folded into Z)

template<int FO, bool LAST>
__global__ __launch_bounds__(256, 4)
void gather_kernel(const int* __restrict__ adj,          // [16][N]
                   const unsigned short* __restrict__ Z, // [N][FO] bf16
                   const unsigned short* __restrict__ U, // [N][FO] bf16
                   void* __restrict__ outp,              // [N][FO] bf16 or f32
                   int N)
{
    constexpr int NL  = FO / 8;     // lanes per node (16 or 8)
    constexpr int NPB = 256 / NL;   // nodes per block
    const int tid = threadIdx.x;
    const int l   = tid & 63;
    const int j   = l & (NL - 1);
    const int nib = (tid >> 6) * (64 / NL) + (l / NL);
    const int n0  = blockIdx.x * NPB + nib;
    const int n   = (n0 < N) ? n0 : (N - 1);
    const int gbase = l & ~(NL - 1);      // wave-lane base of this node's group

    // lane j holds idx for k=j (and k=j+8 when NL==8)
    const int idxv  = adj[(size_t)j * N + n];
    const int idxv2 = (NL == 8) ? adj[(size_t)(j + 8) * N + n] : 0;

    // issue all 16 gather loads up front (MLP)
    uint4 zr[KNBR];
    #pragma unroll
    for (int k = 0; k < KNBR; ++k) {
        int src;
        if (NL == 16) src = __shfl(idxv, gbase + k, 64);
        else          src = (k < 8) ? __shfl(idxv,  gbase + k, 64)
                                    : __shfl(idxv2, gbase + (k - 8), 64);
        zr[k] = *reinterpret_cast<const uint4*>(&Z[(size_t)src * FO + j * 8]);
    }

    float acc[8];
    {
        const uint4 uv = *reinterpret_cast<const uint4*>(&U[(size_t)n * FO + j * 8]);
        acc[0] = bf2f((unsigned short)(uv.x & 0xFFFFu));
        acc[1] = bf2f((unsigned short)(uv.x >> 16));
        acc[2] = bf2f((unsigned short)(uv.y & 0xFFFFu));
        acc[3] = bf2f((unsigned short)(uv.y >> 16));
        acc[4] = bf2f((unsigned short)(uv.z & 0xFFFFu));
        acc[5] = bf2f((unsigned short)(uv.z >> 16));
        acc[6] = bf2f((unsigned short)(uv.w & 0xFFFFu));
        acc[7] = bf2f((unsigned short)(uv.w >> 16));
    }
    #pragma unroll
    for (int k = 0; k < KNBR; ++k) acc8(zr[k], acc);

    if (n0 < N) {
        if (LAST) {
            float* out = (float*)outp;
            float4 v0 = {acc[0], acc[1], acc[2], acc[3]};
            float4 v1 = {acc[4], acc[5], acc[6], acc[7]};
            *reinterpret_cast<float4*>(&out[(size_t)n * FO + j * 8])     = v0;
            *reinterpret_cast<float4*>(&out[(size_t)n * FO + j * 8 + 4]) = v1;
        } else {
            unsigned short* out = (unsigned short*)outp;
            uint4 o;
            o.x = (unsigned int)f2bf(fmaxf(acc[0], 0.f)) | ((unsigned int)f2bf(fmaxf(acc[1], 0.f)) << 16);
            o.y = (unsigned int)f2bf(fmaxf(acc[2], 0.f)) | ((unsigned int)f2bf(fmaxf(acc[3], 0.f)) << 16);
            o.z = (unsigned int)f2bf(fmaxf(acc[4], 0.f)) | ((unsigned int)f2bf(fmaxf(acc[5], 0.f)) << 16);
            o.w = (unsigned int)f2bf(fmaxf(acc[6], 0.f)) | ((unsigned int)f2bf(fmaxf(acc[7], 0.f)) << 16);
            *reinterpret_cast<uint4*>(&out[(size_t)n * FO + j * 8]) = o;
        }
    }
}

extern "C" void kernel_launch(void* const* d_in, const int* in_sizes, int n_in,
                              void* d_out, int out_size, void* d_ws, size_t ws_size,
                              hipStream_t stream) {
    const int N = 50000;

    const float* x   = (const float*)d_in[0];
    const int*   adj = (const int*)  d_in[1];
    const float* W0  = (const float*)d_in[2];
    const float* W1  = (const float*)d_in[3];
    const float* W2  = (const float*)d_in[4];
    float* logits = (float*)d_out;

    char* ws = (char*)d_ws;
    unsigned short* h1  = (unsigned short*)(ws);                      // 12.8 MB
    unsigned short* h2  = (unsigned short*)(ws + 12800000);           // 12.8 MB
    unsigned short* U   = (unsigned short*)(ws + 25600000);           // 12.8 MB
    unsigned short* Z   = (unsigned short*)(ws + 38400000);           // 12.8 MB
    unsigned short* Wc0 = (unsigned short*)(ws + 51200000);           // 64 KB
    unsigned short* Wc1 = (unsigned short*)(ws + 51200000 + 65536);   // 64 KB
    unsigned short* Wc2 = (unsigned short*)(ws + 51200000 + 131072);  // 32 KB

    wc_all_kernel<<<320, 256, 0, stream>>>(W0, W1, W2, Wc0, Wc1, Wc2);

    const int gridD   = (N + 63) / 64;    // 782
    const int gridG128 = N / 16;          // 3125 (exact)
    const int gridG64  = (N + 31) / 32;   // 1563

    // layer 1
    dense_kernel<true, 128><<<gridD, 256, 0, stream>>>(x, Wc0, U, Z, N);
    gather_kernel<128, false><<<gridG128, 256, 0, stream>>>(adj, Z, U, h1, N);
    // layer 2
    dense_kernel<false, 128><<<gridD, 256, 0, stream>>>(h1, Wc1, U, Z, N);
    gather_kernel<128, false><<<gridG128, 256, 0, stream>>>(adj, Z, U, h2, N);
    // layer 3
    dense_kernel<false, 64><<<gridD, 256, 0, stream>>>(h2, Wc2, U, Z, N);
    gather_kernel<64, true><<<gridG64, 256, 0, stream>>>(adj, Z, U, logits, N);
}

// Round 5
// 85.640 us; speedup vs baseline: 1.5061x; 1.5061x over previous
//
#include <hip/hip_runtime.h>

// GraphSAGE forward, 3 layers. R5 = R2 fused structure (best: 114.7us)
// + fp8 e4m3 shadow copy of h for the GATHER path only.
// Self/concat + GEMM stay bf16, accumulation f32.

#define KNBR 16
#define MT   64     // nodes per block
#define LDA  272    // padded LDS row stride in bf16 elems

typedef __attribute__((ext_vector_type(8))) short short8;
typedef __attribute__((ext_vector_type(4))) float f32x4;
typedef __attribute__((ext_vector_type(2))) float f32x2;

__device__ inline float bf2f(unsigned short u) {
    union { unsigned int i; float f; } c; c.i = ((unsigned int)u) << 16; return c.f;
}
__device__ inline unsigned short f2bf(float f) {
    union { float f; unsigned int i; } c; c.f = f;
    unsigned int u = c.i;
    u += 0x7FFFu + ((u >> 16) & 1u);   // RNE
    return (unsigned short)(u >> 16);
}
__device__ inline unsigned char f2fp8(float v) {
    return (unsigned char)(__builtin_amdgcn_cvt_pk_fp8_f32(v, v, 0, false) & 0xFF);
}

// ---------------- prep kernels ----------------

__global__ __launch_bounds__(256)
void cvt_x_kernel(const float* __restrict__ x, unsigned short* __restrict__ xb,
                  unsigned char* __restrict__ xq, int total4) {
    int i = blockIdx.x * 256 + threadIdx.x;
    if (i < total4) {
        float4 v = reinterpret_cast<const float4*>(x)[i];
        ushort4 o;
        o.x = f2bf(v.x); o.y = f2bf(v.y); o.z = f2bf(v.z); o.w = f2bf(v.w);
        reinterpret_cast<ushort4*>(xb)[i] = o;
        unsigned int q;
        q  = __builtin_amdgcn_cvt_pk_fp8_f32(v.x, v.y, 0, false);
        q  = __builtin_amdgcn_cvt_pk_fp8_f32(v.z, v.w, q, true);
        reinterpret_cast<unsigned int*>(xq)[i] = q;
    }
}

// All three W transposes. Wt[j][k] = bf16(W[k][j]); W: [256][FO], Wt: [FO][256]
__global__ __launch_bounds__(256)
void wt_all_kernel(const float* __restrict__ W0, const float* __restrict__ W1,
                   const float* __restrict__ W2,
                   unsigned short* __restrict__ Wt0, unsigned short* __restrict__ Wt1,
                   unsigned short* __restrict__ Wt2) {
    int id = blockIdx.x * 256 + threadIdx.x;
    const float* W; unsigned short* Wt; int FO; int loc;
    if (id < 32768)        { W = W0; Wt = Wt0; FO = 128; loc = id; }
    else if (id < 65536)   { W = W1; Wt = Wt1; FO = 128; loc = id - 32768; }
    else if (id < 81920)   { W = W2; Wt = Wt2; FO = 64;  loc = id - 65536; }
    else return;
    int j = loc >> 8;
    int k = loc & 255;
    Wt[loc] = f2bf(W[k * FO + j]);
}

// ---------------- layer kernel ----------------

template<int FO, bool RELU, bool OUTF32, bool WRITEQ>
__global__ __launch_bounds__(256, 3)
void sage_layer(const unsigned short* __restrict__ h,   // [N][128] bf16 (self path)
                const unsigned char*  __restrict__ hq,  // [N][128] fp8 (gather path)
                const int* __restrict__ adj,            // [16][N]
                const unsigned short* __restrict__ Wt,  // [FO][256] bf16 (transposed W)
                void* __restrict__ outp,                // [N][FO] bf16 or f32
                unsigned char* __restrict__ outq,       // [N][FO] fp8 shadow (if WRITEQ)
                int N)
{
    __shared__ unsigned short A[MT][LDA];   // hcat tile: [0..127]=self, [128..255]=agg
    __shared__ int idxs[MT][KNBR];

    const int tid  = threadIdx.x;
    const int base = blockIdx.x * MT;

    // ---- phase 0: neighbor indices -> LDS (coalesced over n) ----
    {
        const int nn = tid & 63;
        const int q  = tid >> 6;            // 0..3
        int n = base + nn; if (n >= N) n = N - 1;
        #pragma unroll
        for (int rep = 0; rep < 4; ++rep) {
            const int kk = rep * 4 + q;
            idxs[nn][kk] = adj[(size_t)kk * N + n];
        }
    }
    __syncthreads();

    // ---- phase 1: fp8 gather + mean (f32 accum) -> bf16 LDS tile ----
    {
        const int lane16 = tid & 15;
        const int grp    = tid >> 4;        // 0..15
        const int f0     = lane16 * 8;      // feature offset (8 feats/lane)
        #pragma unroll
        for (int i = 0; i < 4; ++i) {
            const int ln = grp * 4 + i;
            int n = base + ln; if (n >= N) n = N - 1;
            // self row: bf16 passthrough, 16B
            const uint4 selfv = *reinterpret_cast<const uint4*>(&h[(size_t)n * 128 + f0]);
            *reinterpret_cast<uint4*>(&A[ln][f0]) = selfv;
            // neighbor mean from fp8 rows (8B/lane, 128B/row coalesced)
            float s[8];
            #pragma unroll
            for (int e = 0; e < 8; ++e) s[e] = 0.f;
            #pragma unroll
            for (int k = 0; k < KNBR; ++k) {
                const int id = idxs[ln][k];
                const uint2 v = *reinterpret_cast<const uint2*>(&hq[(size_t)id * 128 + f0]);
                const f32x2 p0 = __builtin_amdgcn_cvt_pk_f32_fp8(v.x, false);
                const f32x2 p1 = __builtin_amdgcn_cvt_pk_f32_fp8(v.x, true);
                const f32x2 p2 = __builtin_amdgcn_cvt_pk_f32_fp8(v.y, false);
                const f32x2 p3 = __builtin_amdgcn_cvt_pk_f32_fp8(v.y, true);
                s[0] += p0.x; s[1] += p0.y;
                s[2] += p1.x; s[3] += p1.y;
                s[4] += p2.x; s[5] += p2.y;
                s[6] += p3.x; s[7] += p3.y;
            }
            uint4 packed;
            packed.x = (unsigned int)f2bf(s[0] * 0.0625f) | ((unsigned int)f2bf(s[1] * 0.0625f) << 16);
            packed.y = (unsigned int)f2bf(s[2] * 0.0625f) | ((unsigned int)f2bf(s[3] * 0.0625f) << 16);
            packed.z = (unsigned int)f2bf(s[4] * 0.0625f) | ((unsigned int)f2bf(s[5] * 0.0625f) << 16);
            packed.w = (unsigned int)f2bf(s[6] * 0.0625f) | ((unsigned int)f2bf(s[7] * 0.0625f) << 16);
            *reinterpret_cast<uint4*>(&A[ln][128 + f0]) = packed;
        }
    }
    __syncthreads();

    // ---- phase 2: [64 x 256] @ [256 x FO] via mfma_f32_16x16x32_bf16 ----
    {
        constexpr int NCT = FO / 64;        // col-tiles per wave
        const int wv  = tid >> 6;
        const int l   = tid & 63;
        const int l15 = l & 15;
        const int kg  = l >> 4;

        f32x4 acc[4][NCT];
        #pragma unroll
        for (int rt = 0; rt < 4; ++rt)
            #pragma unroll
            for (int c = 0; c < NCT; ++c)
                acc[rt][c] = (f32x4){0.f, 0.f, 0.f, 0.f};

        const unsigned short* wbase[NCT];
        #pragma unroll
        for (int c = 0; c < NCT; ++c) {
            const int col = (wv * NCT + c) * 16 + l15;
            wbase[c] = Wt + (size_t)col * 256 + kg * 8;
        }

        short8 bcur[NCT], bnxt[NCT];
        #pragma unroll
        for (int c = 0; c < NCT; ++c)
            bcur[c] = *reinterpret_cast<const short8*>(wbase[c]);

        #pragma unroll
        for (int ks = 0; ks < 8; ++ks) {
            if (ks < 7) {
                #pragma unroll
                for (int c = 0; c < NCT; ++c)
                    bnxt[c] = *reinterpret_cast<const short8*>(wbase[c] + (ks + 1) * 32);
            }
            #pragma unroll
            for (int rt = 0; rt < 4; ++rt) {
                const short8 a = *reinterpret_cast<const short8*>(&A[rt * 16 + l15][ks * 32 + kg * 8]);
                #pragma unroll
                for (int c = 0; c < NCT; ++c)
                    acc[rt][c] = __builtin_amdgcn_mfma_f32_16x16x32_bf16(a, bcur[c], acc[rt][c], 0, 0, 0);
            }
            #pragma unroll
            for (int c = 0; c < NCT; ++c) bcur[c] = bnxt[c];
        }

        // epilogue: D col = lane&15 (within tile), row = 4*(lane>>4)+reg
        #pragma unroll
        for (int rt = 0; rt < 4; ++rt) {
            #pragma unroll
            for (int c = 0; c < NCT; ++c) {
                const int col = (wv * NCT + c) * 16 + l15;
                #pragma unroll
                for (int r = 0; r < 4; ++r) {
                    const int row = rt * 16 + kg * 4 + r;
                    const int n   = base + row;
                    if (n < N) {
                        float v = acc[rt][c][r];
                        if (RELU) v = fmaxf(v, 0.f);
                        if (OUTF32)
                            reinterpret_cast<float*>(outp)[(size_t)n * FO + col] = v;
                        else
                            reinterpret_cast<unsigned short*>(outp)[(size_t)n * FO + col] = f2bf(v);
                        if (WRITEQ)
                            outq[(size_t)n * FO + col] = f2fp8(v);
                    }
                }
            }
        }
    }
}

extern "C" void kernel_launch(void* const* d_in, const int* in_sizes, int n_in,
                              void* d_out, int out_size, void* d_ws, size_t ws_size,
                              hipStream_t stream) {
    const int N = 50000;
    const int F = 128;

    const float* x   = (const float*)d_in[0];
    const int*   adj = (const int*)  d_in[1];
    const float* W0  = (const float*)d_in[2];
    const float* W1  = (const float*)d_in[3];
    const float* W2  = (const float*)d_in[4];
    float* logits = (float*)d_out;

    char* ws = (char*)d_ws;
    unsigned short* xb  = (unsigned short*)(ws);                     // 12.8 MB
    unsigned short* h1  = (unsigned short*)(ws + 12800000);          // 12.8 MB
    unsigned short* h2  = (unsigned short*)(ws + 25600000);          // 12.8 MB
    unsigned char*  xq  = (unsigned char*) (ws + 38400000);          // 6.4 MB
    unsigned char*  h1q = (unsigned char*) (ws + 44800000);          // 6.4 MB
    unsigned char*  h2q = (unsigned char*) (ws + 51200000);          // 6.4 MB
    unsigned short* Wt0 = (unsigned short*)(ws + 57600000);          // 64 KB
    unsigned short* Wt1 = (unsigned short*)(ws + 57600000 + 65536);  // 64 KB
    unsigned short* Wt2 = (unsigned short*)(ws + 57600000 + 131072); // 32 KB

    cvt_x_kernel<<<(N * F / 4 + 255) / 256, 256, 0, stream>>>(x, xb, xq, N * F / 4);
    wt_all_kernel<<<320, 256, 0, stream>>>(W0, W1, W2, Wt0, Wt1, Wt2);

    const int grid = (N + MT - 1) / MT;   // 782

    sage_layer<128, true,  false, true ><<<grid, 256, 0, stream>>>(xb, xq,  adj, Wt0, h1,     h1q, N);
    sage_layer<128, true,  false, true ><<<grid, 256, 0, stream>>>(h1, h1q, adj, Wt1, h2,     h2q, N);
    sage_layer< 64, false, true,  false><<<grid, 256, 0, stream>>>(h2, h2q, adj, Wt2, logits, nullptr, N);
}

// Round 6
// 85.240 us; speedup vs baseline: 1.5132x; 1.0047x over previous
//
#include <hip/hip_runtime.h>

// GraphSAGE forward, 3 layers. R6 = R5 (fused, fp8 gather path)
// + packed f32x2 accumulation in phase 1, 4 blocks/CU, leaner phase 2.

#define KNBR 16
#define MT   64     // nodes per block
#define LDA  272    // padded LDS row stride in bf16 elems

typedef __attribute__((ext_vector_type(8))) short short8;
typedef __attribute__((ext_vector_type(4))) float f32x4;
typedef __attribute__((ext_vector_type(2))) float f32x2;

__device__ inline float bf2f(unsigned short u) {
    union { unsigned int i; float f; } c; c.i = ((unsigned int)u) << 16; return c.f;
}
__device__ inline unsigned short f2bf(float f) {
    union { float f; unsigned int i; } c; c.f = f;
    unsigned int u = c.i;
    u += 0x7FFFu + ((u >> 16) & 1u);   // RNE
    return (unsigned short)(u >> 16);
}
__device__ inline unsigned char f2fp8(float v) {
    return (unsigned char)(__builtin_amdgcn_cvt_pk_fp8_f32(v, v, 0, false) & 0xFF);
}

// ---------------- prep kernels ----------------

__global__ __launch_bounds__(256)
void cvt_x_kernel(const float* __restrict__ x, unsigned short* __restrict__ xb,
                  unsigned char* __restrict__ xq, int total4) {
    int i = blockIdx.x * 256 + threadIdx.x;
    if (i < total4) {
        float4 v = reinterpret_cast<const float4*>(x)[i];
        ushort4 o;
        o.x = f2bf(v.x); o.y = f2bf(v.y); o.z = f2bf(v.z); o.w = f2bf(v.w);
        reinterpret_cast<ushort4*>(xb)[i] = o;
        unsigned int q;
        q  = __builtin_amdgcn_cvt_pk_fp8_f32(v.x, v.y, 0, false);
        q  = __builtin_amdgcn_cvt_pk_fp8_f32(v.z, v.w, q, true);
        reinterpret_cast<unsigned int*>(xq)[i] = q;
    }
}

// All three W transposes. Wt[j][k] = bf16(W[k][j]); W: [256][FO], Wt: [FO][256]
__global__ __launch_bounds__(256)
void wt_all_kernel(const float* __restrict__ W0, const float* __restrict__ W1,
                   const float* __restrict__ W2,
                   unsigned short* __restrict__ Wt0, unsigned short* __restrict__ Wt1,
                   unsigned short* __restrict__ Wt2) {
    int id = blockIdx.x * 256 + threadIdx.x;
    const float* W; unsigned short* Wt; int FO; int loc;
    if (id < 32768)        { W = W0; Wt = Wt0; FO = 128; loc = id; }
    else if (id < 65536)   { W = W1; Wt = Wt1; FO = 128; loc = id - 32768; }
    else if (id < 81920)   { W = W2; Wt = Wt2; FO = 64;  loc = id - 65536; }
    else return;
    int j = loc >> 8;
    int k = loc & 255;
    Wt[loc] = f2bf(W[k * FO + j]);
}

// ---------------- layer kernel ----------------

template<int FO, bool RELU, bool OUTF32, bool WRITEQ>
__global__ __launch_bounds__(256, 4)
void sage_layer(const unsigned short* __restrict__ h,   // [N][128] bf16 (self path)
                const unsigned char*  __restrict__ hq,  // [N][128] fp8 (gather path)
                const int* __restrict__ adj,            // [16][N]
                const unsigned short* __restrict__ Wt,  // [FO][256] bf16 (transposed W)
                void* __restrict__ outp,                // [N][FO] bf16 or f32
                unsigned char* __restrict__ outq,       // [N][FO] fp8 shadow (if WRITEQ)
                int N)
{
    __shared__ unsigned short A[MT][LDA];   // hcat tile: [0..127]=self, [128..255]=agg
    __shared__ int idxs[MT][KNBR];

    const int tid  = threadIdx.x;
    const int base = blockIdx.x * MT;

    // ---- phase 0: neighbor indices -> LDS (coalesced over n) ----
    {
        const int nn = tid & 63;
        const int q  = tid >> 6;            // 0..3
        int n = base + nn; if (n >= N) n = N - 1;
        #pragma unroll
        for (int rep = 0; rep < 4; ++rep) {
            const int kk = rep * 4 + q;
            idxs[nn][kk] = adj[(size_t)kk * N + n];
        }
    }
    __syncthreads();

    // ---- phase 1: fp8 gather + packed mean (f32x2 accum) -> bf16 LDS tile ----
    {
        const int lane16 = tid & 15;
        const int grp    = tid >> 4;        // 0..15
        const int f0     = lane16 * 8;      // feature offset (8 feats/lane)
        #pragma unroll
        for (int i = 0; i < 4; ++i) {
            const int ln = grp * 4 + i;
            int n = base + ln; if (n >= N) n = N - 1;
            // self row: bf16 passthrough, 16B
            const uint4 selfv = *reinterpret_cast<const uint4*>(&h[(size_t)n * 128 + f0]);
            *reinterpret_cast<uint4*>(&A[ln][f0]) = selfv;
            // neighbor mean from fp8 rows (8B/lane, 128B/row coalesced)
            f32x2 s01 = {0.f, 0.f}, s23 = {0.f, 0.f}, s45 = {0.f, 0.f}, s67 = {0.f, 0.f};
            #pragma unroll
            for (int k = 0; k < KNBR; ++k) {
                const int id = idxs[ln][k];
                const uint2 v = *reinterpret_cast<const uint2*>(&hq[(size_t)id * 128 + f0]);
                s01 += __builtin_amdgcn_cvt_pk_f32_fp8(v.x, false);   // v_pk_add_f32
                s23 += __builtin_amdgcn_cvt_pk_f32_fp8(v.x, true);
                s45 += __builtin_amdgcn_cvt_pk_f32_fp8(v.y, false);
                s67 += __builtin_amdgcn_cvt_pk_f32_fp8(v.y, true);
            }
            uint4 packed;
            packed.x = (unsigned int)f2bf(s01.x * 0.0625f) | ((unsigned int)f2bf(s01.y * 0.0625f) << 16);
            packed.y = (unsigned int)f2bf(s23.x * 0.0625f) | ((unsigned int)f2bf(s23.y * 0.0625f) << 16);
            packed.z = (unsigned int)f2bf(s45.x * 0.0625f) | ((unsigned int)f2bf(s45.y * 0.0625f) << 16);
            packed.w = (unsigned int)f2bf(s67.x * 0.0625f) | ((unsigned int)f2bf(s67.y * 0.0625f) << 16);
            *reinterpret_cast<uint4*>(&A[ln][128 + f0]) = packed;
        }
    }
    __syncthreads();

    // ---- phase 2: [64 x 256] @ [256 x FO] via mfma_f32_16x16x32_bf16 ----
    {
        constexpr int NCT = FO / 64;        // col-tiles per wave
        const int wv  = tid >> 6;
        const int l   = tid & 63;
        const int l15 = l & 15;
        const int kg  = l >> 4;

        f32x4 acc[4][NCT];
        #pragma unroll
        for (int rt = 0; rt < 4; ++rt)
            #pragma unroll
            for (int c = 0; c < NCT; ++c)
                acc[rt][c] = (f32x4){0.f, 0.f, 0.f, 0.f};

        const unsigned short* wbase[NCT];
        #pragma unroll
        for (int c = 0; c < NCT; ++c) {
            const int col = (wv * NCT + c) * 16 + l15;
            wbase[c] = Wt + (size_t)col * 256 + kg * 8;
        }

        #pragma unroll
        for (int ks = 0; ks < 8; ++ks) {
            short8 b[NCT];
            #pragma unroll
            for (int c = 0; c < NCT; ++c)
                b[c] = *reinterpret_cast<const short8*>(wbase[c] + ks * 32);
            #pragma unroll
            for (int rt = 0; rt < 4; ++rt) {
                const short8 a = *reinterpret_cast<const short8*>(&A[rt * 16 + l15][ks * 32 + kg * 8]);
                #pragma unroll
                for (int c = 0; c < NCT; ++c)
                    acc[rt][c] = __builtin_amdgcn_mfma_f32_16x16x32_bf16(a, b[c], acc[rt][c], 0, 0, 0);
            }
        }

        // epilogue: D col = lane&15 (within tile), row = 4*(lane>>4)+reg
        #pragma unroll
        for (int rt = 0; rt < 4; ++rt) {
            #pragma unroll
            for (int c = 0; c < NCT; ++c) {
                const int col = (wv * NCT + c) * 16 + l15;
                #pragma unroll
                for (int r = 0; r < 4; ++r) {
                    const int row = rt * 16 + kg * 4 + r;
                    const int n   = base + row;
                    if (n < N) {
                        float v = acc[rt][c][r];
                        if (RELU) v = fmaxf(v, 0.f);
                        if (OUTF32)
                            reinterpret_cast<float*>(outp)[(size_t)n * FO + col] = v;
                        else
                            reinterpret_cast<unsigned short*>(outp)[(size_t)n * FO + col] = f2bf(v);
                        if (WRITEQ)
                            outq[(size_t)n * FO + col] = f2fp8(v);
                    }
                }
            }
        }
    }
}

extern "C" void kernel_launch(void* const* d_in, const int* in_sizes, int n_in,
                              void* d_out, int out_size, void* d_ws, size_t ws_size,
                              hipStream_t stream) {
    const int N = 50000;
    const int F = 128;

    const float* x   = (const float*)d_in[0];
    const int*   adj = (const int*)  d_in[1];
    const float* W0  = (const float*)d_in[2];
    const float* W1  = (const float*)d_in[3];
    const float* W2  = (const float*)d_in[4];
    float* logits = (float*)d_out;

    char* ws = (char*)d_ws;
    unsigned short* xb  = (unsigned short*)(ws);                     // 12.8 MB
    unsigned short* h1  = (unsigned short*)(ws + 12800000);          // 12.8 MB
    unsigned short* h2  = (unsigned short*)(ws + 25600000);          // 12.8 MB
    unsigned char*  xq  = (unsigned char*) (ws + 38400000);          // 6.4 MB
    unsigned char*  h1q = (unsigned char*) (ws + 44800000);          // 6.4 MB
    unsigned char*  h2q = (unsigned char*) (ws + 51200000);          // 6.4 MB
    unsigned short* Wt0 = (unsigned short*)(ws + 57600000);          // 64 KB
    unsigned short* Wt1 = (unsigned short*)(ws + 57600000 + 65536);  // 64 KB
    unsigned short* Wt2 = (unsigned short*)(ws + 57600000 + 131072); // 32 KB

    cvt_x_kernel<<<(N * F / 4 + 255) / 256, 256, 0, stream>>>(x, xb, xq, N * F / 4);
    wt_all_kernel<<<320, 256, 0, stream>>>(W0, W1, W2, Wt0, Wt1, Wt2);

    const int grid = (N + MT - 1) / MT;   // 782

    sage_layer<128, true,  false, true ><<<grid, 256, 0, stream>>>(xb, xq,  adj, Wt0, h1,     h1q, N);
    sage_layer<128, true,  false, true ><<<grid, 256, 0, stream>>>(h1, h1q, adj, Wt1, h2,     h2q, N);
    sage_layer< 64, false, true,  false><<<grid, 256, 0, stream>>>(h2, h2q, adj, Wt2, logits, nullptr, N);
}

// Round 7
// 83.514 us; speedup vs baseline: 1.5444x; 1.0207x over previous
//
#include <hip/hip_runtime.h>

// GraphSAGE forward, 3 layers. R7 = R6 (fused, fp8 gather path)
// + phase-1 restructured for 2x memory-level parallelism:
//   issue 32 gather loads (2 nodes x 16 neighbors) before accumulating.

#define KNBR 16
#define MT   64     // nodes per block
#define LDA  272    // padded LDS row stride in bf16 elems

typedef __attribute__((ext_vector_type(8))) short short8;
typedef __attribute__((ext_vector_type(4))) float f32x4;
typedef __attribute__((ext_vector_type(2))) float f32x2;

__device__ inline float bf2f(unsigned short u) {
    union { unsigned int i; float f; } c; c.i = ((unsigned int)u) << 16; return c.f;
}
__device__ inline unsigned short f2bf(float f) {
    union { float f; unsigned int i; } c; c.f = f;
    unsigned int u = c.i;
    u += 0x7FFFu + ((u >> 16) & 1u);   // RNE
    return (unsigned short)(u >> 16);
}
__device__ inline unsigned char f2fp8(float v) {
    return (unsigned char)(__builtin_amdgcn_cvt_pk_fp8_f32(v, v, 0, false) & 0xFF);
}

// ---------------- prep kernels ----------------

__global__ __launch_bounds__(256)
void cvt_x_kernel(const float* __restrict__ x, unsigned short* __restrict__ xb,
                  unsigned char* __restrict__ xq, int total4) {
    int i = blockIdx.x * 256 + threadIdx.x;
    if (i < total4) {
        float4 v = reinterpret_cast<const float4*>(x)[i];
        ushort4 o;
        o.x = f2bf(v.x); o.y = f2bf(v.y); o.z = f2bf(v.z); o.w = f2bf(v.w);
        reinterpret_cast<ushort4*>(xb)[i] = o;
        unsigned int q;
        q  = __builtin_amdgcn_cvt_pk_fp8_f32(v.x, v.y, 0, false);
        q  = __builtin_amdgcn_cvt_pk_fp8_f32(v.z, v.w, q, true);
        reinterpret_cast<unsigned int*>(xq)[i] = q;
    }
}

// All three W transposes. Wt[j][k] = bf16(W[k][j]); W: [256][FO], Wt: [FO][256]
__global__ __launch_bounds__(256)
void wt_all_kernel(const float* __restrict__ W0, const float* __restrict__ W1,
                   const float* __restrict__ W2,
                   unsigned short* __restrict__ Wt0, unsigned short* __restrict__ Wt1,
                   unsigned short* __restrict__ Wt2) {
    int id = blockIdx.x * 256 + threadIdx.x;
    const float* W; unsigned short* Wt; int FO; int loc;
    if (id < 32768)        { W = W0; Wt = Wt0; FO = 128; loc = id; }
    else if (id < 65536)   { W = W1; Wt = Wt1; FO = 128; loc = id - 32768; }
    else if (id < 81920)   { W = W2; Wt = Wt2; FO = 64;  loc = id - 65536; }
    else return;
    int j = loc >> 8;
    int k = loc & 255;
    Wt[loc] = f2bf(W[k * FO + j]);
}

// ---------------- layer kernel ----------------

template<int FO, bool RELU, bool OUTF32, bool WRITEQ>
__global__ __launch_bounds__(256, 4)
void sage_layer(const unsigned short* __restrict__ h,   // [N][128] bf16 (self path)
                const unsigned char*  __restrict__ hq,  // [N][128] fp8 (gather path)
                const int* __restrict__ adj,            // [16][N]
                const unsigned short* __restrict__ Wt,  // [FO][256] bf16 (transposed W)
                void* __restrict__ outp,                // [N][FO] bf16 or f32
                unsigned char* __restrict__ outq,       // [N][FO] fp8 shadow (if WRITEQ)
                int N)
{
    __shared__ unsigned short A[MT][LDA];   // hcat tile: [0..127]=self, [128..255]=agg
    __shared__ int idxs[MT][KNBR];

    const int tid  = threadIdx.x;
    const int base = blockIdx.x * MT;

    // ---- phase 0: neighbor indices -> LDS (coalesced over n) ----
    {
        const int nn = tid & 63;
        const int q  = tid >> 6;            // 0..3
        int n = base + nn; if (n >= N) n = N - 1;
        #pragma unroll
        for (int rep = 0; rep < 4; ++rep) {
            const int kk = rep * 4 + q;
            idxs[nn][kk] = adj[(size_t)kk * N + n];
        }
    }
    __syncthreads();

    // ---- phase 1: fp8 gather, node-PAIR interleaved (32 loads in flight) ----
    {
        const int lane16 = tid & 15;
        const int grp    = tid >> 4;        // 0..15
        const int f0     = lane16 * 8;      // feature offset (8 feats/lane)
        #pragma unroll
        for (int i = 0; i < 2; ++i) {       // 2 pairs -> 4 nodes per 16-lane group
            const int lnA = grp * 4 + i * 2;
            const int lnB = lnA + 1;
            int nA = base + lnA; if (nA >= N) nA = N - 1;
            int nB = base + lnB; if (nB >= N) nB = N - 1;

            // self rows (bf16 passthrough, 16B each)
            const uint4 selfA = *reinterpret_cast<const uint4*>(&h[(size_t)nA * 128 + f0]);
            const uint4 selfB = *reinterpret_cast<const uint4*>(&h[(size_t)nB * 128 + f0]);
            *reinterpret_cast<uint4*>(&A[lnA][f0]) = selfA;
            *reinterpret_cast<uint4*>(&A[lnB][f0]) = selfB;

            // issue ALL 32 gather loads before accumulating (MLP)
            uint2 va[KNBR], vb[KNBR];
            #pragma unroll
            for (int k = 0; k < KNBR; ++k)
                va[k] = *reinterpret_cast<const uint2*>(&hq[(size_t)idxs[lnA][k] * 128 + f0]);
            #pragma unroll
            for (int k = 0; k < KNBR; ++k)
                vb[k] = *reinterpret_cast<const uint2*>(&hq[(size_t)idxs[lnB][k] * 128 + f0]);

            // accumulate A
            f32x2 a01 = {0.f,0.f}, a23 = {0.f,0.f}, a45 = {0.f,0.f}, a67 = {0.f,0.f};
            #pragma unroll
            for (int k = 0; k < KNBR; ++k) {
                a01 += __builtin_amdgcn_cvt_pk_f32_fp8(va[k].x, false);
                a23 += __builtin_amdgcn_cvt_pk_f32_fp8(va[k].x, true);
                a45 += __builtin_amdgcn_cvt_pk_f32_fp8(va[k].y, false);
                a67 += __builtin_amdgcn_cvt_pk_f32_fp8(va[k].y, true);
            }
            uint4 pA;
            pA.x = (unsigned int)f2bf(a01.x * 0.0625f) | ((unsigned int)f2bf(a01.y * 0.0625f) << 16);
            pA.y = (unsigned int)f2bf(a23.x * 0.0625f) | ((unsigned int)f2bf(a23.y * 0.0625f) << 16);
            pA.z = (unsigned int)f2bf(a45.x * 0.0625f) | ((unsigned int)f2bf(a45.y * 0.0625f) << 16);
            pA.w = (unsigned int)f2bf(a67.x * 0.0625f) | ((unsigned int)f2bf(a67.y * 0.0625f) << 16);
            *reinterpret_cast<uint4*>(&A[lnA][128 + f0]) = pA;

            // accumulate B
            f32x2 b01 = {0.f,0.f}, b23 = {0.f,0.f}, b45 = {0.f,0.f}, b67 = {0.f,0.f};
            #pragma unroll
            for (int k = 0; k < KNBR; ++k) {
                b01 += __builtin_amdgcn_cvt_pk_f32_fp8(vb[k].x, false);
                b23 += __builtin_amdgcn_cvt_pk_f32_fp8(vb[k].x, true);
                b45 += __builtin_amdgcn_cvt_pk_f32_fp8(vb[k].y, false);
                b67 += __builtin_amdgcn_cvt_pk_f32_fp8(vb[k].y, true);
            }
            uint4 pB;
            pB.x = (unsigned int)f2bf(b01.x * 0.0625f) | ((unsigned int)f2bf(b01.y * 0.0625f) << 16);
            pB.y = (unsigned int)f2bf(b23.x * 0.0625f) | ((unsigned int)f2bf(b23.y * 0.0625f) << 16);
            pB.z = (unsigned int)f2bf(b45.x * 0.0625f) | ((unsigned int)f2bf(b45.y * 0.0625f) << 16);
            pB.w = (unsigned int)f2bf(b67.x * 0.0625f) | ((unsigned int)f2bf(b67.y * 0.0625f) << 16);
            *reinterpret_cast<uint4*>(&A[lnB][128 + f0]) = pB;
        }
    }
    __syncthreads();

    // ---- phase 2: [64 x 256] @ [256 x FO] via mfma_f32_16x16x32_bf16 ----
    {
        constexpr int NCT = FO / 64;        // col-tiles per wave
        const int wv  = tid >> 6;
        const int l   = tid & 63;
        const int l15 = l & 15;
        const int kg  = l >> 4;

        f32x4 acc[4][NCT];
        #pragma unroll
        for (int rt = 0; rt < 4; ++rt)
            #pragma unroll
            for (int c = 0; c < NCT; ++c)
                acc[rt][c] = (f32x4){0.f, 0.f, 0.f, 0.f};

        const unsigned short* wbase[NCT];
        #pragma unroll
        for (int c = 0; c < NCT; ++c) {
            const int col = (wv * NCT + c) * 16 + l15;
            wbase[c] = Wt + (size_t)col * 256 + kg * 8;
        }

        #pragma unroll
        for (int ks = 0; ks < 8; ++ks) {
            short8 b[NCT];
            #pragma unroll
            for (int c = 0; c < NCT; ++c)
                b[c] = *reinterpret_cast<const short8*>(wbase[c] + ks * 32);
            #pragma unroll
            for (int rt = 0; rt < 4; ++rt) {
                const short8 a = *reinterpret_cast<const short8*>(&A[rt * 16 + l15][ks * 32 + kg * 8]);
                #pragma unroll
                for (int c = 0; c < NCT; ++c)
                    acc[rt][c] = __builtin_amdgcn_mfma_f32_16x16x32_bf16(a, b[c], acc[rt][c], 0, 0, 0);
            }
        }

        // epilogue: D col = lane&15 (within tile), row = 4*(lane>>4)+reg
        #pragma unroll
        for (int rt = 0; rt < 4; ++rt) {
            #pragma unroll
            for (int c = 0; c < NCT; ++c) {
                const int col = (wv * NCT + c) * 16 + l15;
                #pragma unroll
                for (int r = 0; r < 4; ++r) {
                    const int row = rt * 16 + kg * 4 + r;
                    const int n   = base + row;
                    if (n < N) {
                        float v = acc[rt][c][r];
                        if (RELU) v = fmaxf(v, 0.f);
                        if (OUTF32)
                            reinterpret_cast<float*>(outp)[(size_t)n * FO + col] = v;
                        else
                            reinterpret_cast<unsigned short*>(outp)[(size_t)n * FO + col] = f2bf(v);
                        if (WRITEQ)
                            outq[(size_t)n * FO + col] = f2fp8(v);
                    }
                }
            }
        }
    }
}

extern "C" void kernel_launch(void* const* d_in, const int* in_sizes, int n_in,
                              void* d_out, int out_size, void* d_ws, size_t ws_size,
                              hipStream_t stream) {
    const int N = 50000;
    const int F = 128;

    const float* x   = (const float*)d_in[0];
    const int*   adj = (const int*)  d_in[1];
    const float* W0  = (const float*)d_in[2];
    const float* W1  = (const float*)d_in[3];
    const float* W2  = (const float*)d_in[4];
    float* logits = (float*)d_out;

    char* ws = (char*)d_ws;
    unsigned short* xb  = (unsigned short*)(ws);                     // 12.8 MB
    unsigned short* h1  = (unsigned short*)(ws + 12800000);          // 12.8 MB
    unsigned short* h2  = (unsigned short*)(ws + 25600000);          // 12.8 MB
    unsigned char*  xq  = (unsigned char*) (ws + 38400000);          // 6.4 MB
    unsigned char*  h1q = (unsigned char*) (ws + 44800000);          // 6.4 MB
    unsigned char*  h2q = (unsigned char*) (ws + 51200000);          // 6.4 MB
    unsigned short* Wt0 = (unsigned short*)(ws + 57600000);          // 64 KB
    unsigned short* Wt1 = (unsigned short*)(ws + 57600000 + 65536);  // 64 KB
    unsigned short* Wt2 = (unsigned short*)(ws + 57600000 + 131072); // 32 KB

    cvt_x_kernel<<<(N * F / 4 + 255) / 256, 256, 0, stream>>>(x, xb, xq, N * F / 4);
    wt_all_kernel<<<320, 256, 0, stream>>>(W0, W1, W2, Wt0, Wt1, Wt2);

    const int grid = (N + MT - 1) / MT;   // 782

    sage_layer<128, true,  false, true ><<<grid, 256, 0, stream>>>(xb, xq,  adj, Wt0, h1,     h1q, N);
    sage_layer<128, true,  false, true ><<<grid, 256, 0, stream>>>(h1, h1q, adj, Wt1, h2,     h2q, N);
    sage_layer< 64, false, true,  false><<<grid, 256, 0, stream>>>(h2, h2q, adj, Wt2, logits, nullptr, N);
}